// Round 3
// baseline (4725.290 us; speedup 1.0000x reference)
//
#include <hip/hip_runtime.h>

typedef short bf16x8 __attribute__((ext_vector_type(8)));
typedef float f32x4 __attribute__((ext_vector_type(4)));
typedef unsigned short ushort_t;

__device__ inline float bf2f(ushort_t h) {
    return __uint_as_float(((unsigned int)h) << 16);
}
__device__ inline ushort_t f2bf(float f) {
    unsigned int u = __float_as_uint(f);
    unsigned int r = u + 0x7fffu + ((u >> 16) & 1u);   // RNE
    return (ushort_t)(r >> 16);
}

// ---------------------------------------------------------------------------
// C = A(MxK,fp32) * W(NxK,fp32)^T, bf16 MFMA core, fp32 accumulate.
// K = 4096 fixed. 128x128 tile, BK=64, 256 threads. Staging converts
// fp32 -> bf16 (RNE) into XOR-swizzled LDS (slot = chunk ^ (row&7)).
// Up to 3 column segments (W/D/mode/ldc), selected by blockIdx.x.
// dest modes: 0 plain bf16 r*ldc+c; 1 ctx-cache bf16 (b=r>>12,t=r&4095 ->
//   (b*4160+t)*1024+c); 2 noise-cache bf16 (b=r>>6,k=r&63 ->
//   (b*4160+4096+k)*1024+c); 3 plain fp32 r*ldc+c.
// ---------------------------------------------------------------------------
__global__ __launch_bounds__(256) void gemm_bt(
    const float* __restrict__ A, int M,
    const float* __restrict__ W0, void* __restrict__ D0, int nb0, int mode0, int ldc0,
    const float* __restrict__ W1, void* __restrict__ D1, int nb1, int mode1, int ldc1,
    const float* __restrict__ W2, void* __restrict__ D2, int mode2, int ldc2)
{
    __shared__ __align__(16) ushort_t As[128 * 64];
    __shared__ __align__(16) ushort_t Bs[128 * 64];

    const int tid = threadIdx.x;
    const int lane = tid & 63;
    const int wid = tid >> 6;
    const int bn = blockIdx.x, bm = blockIdx.y;

    const float* W; void* D; int mode, ldc, nloc;
    if (bn < nb0)            { W = W0; D = D0; mode = mode0; ldc = ldc0; nloc = bn; }
    else if (bn < nb0 + nb1) { W = W1; D = D1; mode = mode1; ldc = ldc1; nloc = bn - nb0; }
    else                     { W = W2; D = D2; mode = mode2; ldc = ldc2; nloc = bn - nb0 - nb1; }

    const int wm = wid >> 1, wn = wid & 1;
    const int quad = lane >> 4;

    f32x4 acc[4][4];
    for (int mt = 0; mt < 4; mt++)
        for (int nt = 0; nt < 4; nt++)
            acc[mt][nt] = (f32x4)0.0f;

    for (int k0 = 0; k0 < 4096; k0 += 64) {
        __syncthreads();
        for (int it = 0; it < 8; it++) {
            const int u = it * 256 + tid;          // 0..2047
            const int row = u >> 4;                // tile row 0..127
            const int sc4 = u & 15;                // 4-float source group
            const int cs = sc4 >> 1;               // source 16B(bf16x8) chunk
            const int half = sc4 & 1;
            const int slot = cs ^ (row & 7);       // swizzled LDS slot
            const float4 va = *(const float4*)(A + (size_t)(bm * 128 + row) * 4096 + k0 + sc4 * 4);
            const float4 vb = *(const float4*)(W + (size_t)(nloc * 128 + row) * 4096 + k0 + sc4 * 4);
            uint2 pa, pb;
            pa.x = (unsigned int)f2bf(va.x) | ((unsigned int)f2bf(va.y) << 16);
            pa.y = (unsigned int)f2bf(va.z) | ((unsigned int)f2bf(va.w) << 16);
            pb.x = (unsigned int)f2bf(vb.x) | ((unsigned int)f2bf(vb.y) << 16);
            pb.y = (unsigned int)f2bf(vb.z) | ((unsigned int)f2bf(vb.w) << 16);
            *(uint2*)&As[row * 64 + slot * 8 + half * 4] = pa;
            *(uint2*)&Bs[row * 64 + slot * 8 + half * 4] = pb;
        }
        __syncthreads();
        for (int kk = 0; kk < 2; kk++) {
            const int c16b = kk * 4 + quad;
            bf16x8 af[4], bfv[4];
            for (int mt = 0; mt < 4; mt++) {
                const int rm = wm * 64 + mt * 16 + (lane & 15);
                af[mt] = *(const bf16x8*)&As[rm * 64 + ((c16b ^ (rm & 7)) * 8)];
            }
            for (int nt = 0; nt < 4; nt++) {
                const int rn = wn * 64 + nt * 16 + (lane & 15);
                bfv[nt] = *(const bf16x8*)&Bs[rn * 64 + ((c16b ^ (rn & 7)) * 8)];
            }
            for (int mt = 0; mt < 4; mt++)
                for (int nt = 0; nt < 4; nt++)
                    acc[mt][nt] = __builtin_amdgcn_mfma_f32_16x16x32_bf16(
                        af[mt], bfv[nt], acc[mt][nt], 0, 0, 0);
        }
    }

    for (int mt = 0; mt < 4; mt++) {
        for (int nt = 0; nt < 4; nt++) {
            const int c = nloc * 128 + wn * 64 + nt * 16 + (lane & 15);
            for (int rr = 0; rr < 4; rr++) {
                const int r = bm * 128 + wm * 64 + mt * 16 + quad * 4 + rr;
                const float val = acc[mt][nt][rr];
                if (mode == 0) {
                    ((ushort_t*)D)[(size_t)r * ldc + c] = f2bf(val);
                } else if (mode == 1) {
                    int b = r >> 12, t = r & 4095;
                    ((ushort_t*)D)[((size_t)(b * 4160 + t)) * 1024 + c] = f2bf(val);
                } else if (mode == 2) {
                    int b = r >> 6, kq = r & 63;
                    ((ushort_t*)D)[((size_t)(b * 4160 + 4096 + kq)) * 1024 + c] = f2bf(val);
                } else {
                    ((float*)D)[(size_t)r * ldc + c] = val;
                }
            }
        }
    }
}

// ---------------------------------------------------------------------------
// RMSNorm + RoPE, in place on bf16 buffers, one wave per 128-dim head row.
// cos/sin/weight are fp32 inputs.
// mode 0: K-cache rows (B*L*NKV), layout (b*4160+l)*1024 + h*128, pos=b*4160+l
// mode 1: Q rows (B*K*NH), layout (b*64+k)*4096 + h*128, pos=b*4160+4096+k
// ---------------------------------------------------------------------------
__global__ __launch_bounds__(256) void norm_rope(
    ushort_t* __restrict__ X,
    const float* __restrict__ cosb, const float* __restrict__ sinb,
    const float* __restrict__ w, int mode)
{
    const int lane = threadIdx.x & 63;
    const int wid = threadIdx.x >> 6;
    const int rid = blockIdx.x * 4 + wid;

    ushort_t* ptr;
    size_t pos_row;
    if (mode == 0) {
        const int h = rid & 7, tmp = rid >> 3;      // tmp = b*4160 + l
        ptr = X + (size_t)tmp * 1024 + h * 128;
        pos_row = (size_t)tmp;
    } else {
        const int h = rid & 31, tmp = rid >> 5;     // tmp = b*64 + k
        const int k = tmp & 63, b = tmp >> 6;
        ptr = X + (size_t)tmp * 4096 + h * 128;
        pos_row = (size_t)(b * 4160 + 4096 + k);
    }

    float x1 = bf2f(ptr[lane]);
    float x2 = bf2f(ptr[lane + 64]);
    float ss = x1 * x1 + x2 * x2;
    for (int m = 1; m < 64; m <<= 1) ss += __shfl_xor(ss, m, 64);
    const float rn = rsqrtf(ss * (1.0f / 128.0f) + 1e-6f);
    const float y1 = x1 * rn * w[lane];
    const float y2 = x2 * rn * w[lane + 64];

    const float* cr = cosb + pos_row * 128;
    const float* sr = sinb + pos_row * 128;
    ptr[lane]      = f2bf(y1 * cr[lane]      - y2 * sr[lane]);
    ptr[lane + 64] = f2bf(y2 * cr[lane + 64] + y1 * sr[lane + 64]);
}

// ---------------------------------------------------------------------------
// Flash attention: one block = (b, head h, 32-query half), 256 blocks, 256 thr.
// L-chunks of 128, online softmax, MFMA 16x16x32 bf16 for QK^T and PV.
// Q/K/V internal buffers bf16; mask fp32 input; AO output fp32.
// ---------------------------------------------------------------------------
__global__ __launch_bounds__(256) void attn_kernel(
    const ushort_t* __restrict__ Qb, const ushort_t* __restrict__ Kc,
    const ushort_t* __restrict__ Vc, const float* __restrict__ amask,
    float* __restrict__ AO)
{
    __shared__ __align__(16) ushort_t Qs[32 * 136];
    __shared__ __align__(16) ushort_t Ks[128 * 136];
    __shared__ __align__(16) ushort_t Vts[128 * 136];   // transposed: [d][l]
    __shared__ __align__(16) ushort_t Ps[32 * 136];
    __shared__ __align__(16) float Ss[32 * 132];
    __shared__ float mst[32], lst[32], alp[32];

    const int tid = threadIdx.x;
    const int lane = tid & 63;
    const int wid = tid >> 6;
    const int quad = lane >> 4;

    const int bidx = blockIdx.x;
    const int b = bidx >> 6;
    const int rb = bidx & 63;
    const int h = rb >> 1;
    const int k0 = (rb & 1) * 32;
    const int hkv = h >> 2;

    // stage Q tile (32 queries x 128)
    {
        const int row = tid >> 3, j = tid & 7;
        const ushort_t* src = Qb + ((size_t)(b * 64 + k0 + row) * 4096 + h * 128 + j * 16);
        uint4 v0 = *(const uint4*)src;
        uint4 v1 = *(const uint4*)(src + 8);
        *(uint4*)&Qs[row * 136 + j * 16] = v0;
        *(uint4*)&Qs[row * 136 + j * 16 + 8] = v1;
    }
    if (tid < 32) { mst[tid] = -INFINITY; lst[tid] = 0.0f; }
    __syncthreads();

    // Q fragments in registers (reused every chunk)
    bf16x8 aq[2][4];
    for (int mt = 0; mt < 2; mt++)
        for (int kk = 0; kk < 4; kk++)
            aq[mt][kk] = *(const bf16x8*)&Qs[(mt * 16 + (lane & 15)) * 136 + kk * 32 + quad * 8];

    f32x4 acc_o[2][2];
    for (int mt = 0; mt < 2; mt++)
        for (int nt = 0; nt < 2; nt++)
            acc_o[mt][nt] = (f32x4)0.0f;

    const float scale = 0.08838834764831845f;  // 1/sqrt(128)
    const int n0w = wid * 32;
    const int d0w = wid * 32;

    for (int ch = 0; ch < 33; ch++) {
        const int l0 = ch * 128;
        __syncthreads();   // protect LDS from previous chunk's readers

        // stage K chunk (128 l-rows x 128 d)
        {
            const int row = tid >> 1, half = tid & 1;
            const int lg = l0 + row;
            const ushort_t* src = Kc + ((size_t)(b * 4160 + lg) * 1024 + hkv * 128);
            const bool ok = lg < 4160;
            for (int i = 0; i < 8; i++) {
                const int ci = i * 2 + half;       // 16B chunk 0..15
                uint4 v = ok ? *(const uint4*)(src + ci * 8) : make_uint4(0, 0, 0, 0);
                *(uint4*)&Ks[row * 136 + ci * 8] = v;
            }
        }
        // stage V chunk transposed: Vts[d][l]
        for (int it = 0; it < 4; it++) {
            const int dg = wid + 4 * it;           // d-group of 8, 0..15
            const int l = l0 + 2 * lane;
            const ushort_t* src = Vc + ((size_t)(b * 4160 + l) * 1024 + hkv * 128 + dg * 8);
            uint4 va = make_uint4(0, 0, 0, 0), vb = make_uint4(0, 0, 0, 0);
            if (l < 4160)     va = *(const uint4*)src;
            if (l + 1 < 4160) vb = *(const uint4*)(src + 1024);
            const ushort_t* ap = (const ushort_t*)&va;
            const ushort_t* bp = (const ushort_t*)&vb;
            for (int jj = 0; jj < 8; jj++) {
                unsigned int val = (unsigned int)ap[jj] | ((unsigned int)bp[jj] << 16);
                *(unsigned int*)&Vts[(dg * 8 + jj) * 136 + 2 * lane] = val;
            }
        }
        __syncthreads();

        // S = Q K^T  (32 x 128 per block, 32 cols per wave)
        f32x4 sacc[2][2];
        for (int mt = 0; mt < 2; mt++)
            for (int nt = 0; nt < 2; nt++)
                sacc[mt][nt] = (f32x4)0.0f;
        for (int kk = 0; kk < 4; kk++) {
            bf16x8 bk_[2];
            for (int nt = 0; nt < 2; nt++)
                bk_[nt] = *(const bf16x8*)&Ks[(n0w + nt * 16 + (lane & 15)) * 136 + kk * 32 + quad * 8];
            for (int mt = 0; mt < 2; mt++)
                for (int nt = 0; nt < 2; nt++)
                    sacc[mt][nt] = __builtin_amdgcn_mfma_f32_16x16x32_bf16(
                        aq[mt][kk], bk_[nt], sacc[mt][nt], 0, 0, 0);
        }
        // scale + mask -> Ss
        for (int mt = 0; mt < 2; mt++) {
            for (int nt = 0; nt < 2; nt++) {
                const int col = n0w + nt * 16 + (lane & 15);
                const int l = l0 + col;
                for (int rr = 0; rr < 4; rr++) {
                    const int row = mt * 16 + quad * 4 + rr;
                    float s;
                    if (l < 4160) {
                        const float mk = amask[(size_t)(b * 64 + k0 + row) * 4160 + l];
                        s = sacc[mt][nt][rr] * scale + mk;
                    } else s = -3.0e4f;
                    Ss[row * 132 + col] = s;
                }
            }
        }
        __syncthreads();

        // online softmax: 8 lanes per row, 16 cols per lane
        {
            const int rw = wid * 8 + (lane >> 3);
            const int j = lane & 7;
            const float* srow = &Ss[rw * 132 + j * 16];
            float v[16];
            float mx = -INFINITY;
            for (int jj = 0; jj < 16; jj++) { v[jj] = srow[jj]; mx = fmaxf(mx, v[jj]); }
            mx = fmaxf(mx, __shfl_xor(mx, 1, 64));
            mx = fmaxf(mx, __shfl_xor(mx, 2, 64));
            mx = fmaxf(mx, __shfl_xor(mx, 4, 64));
            const float mo = mst[rw];
            const float mn = fmaxf(mo, mx);
            float sum = 0.0f;
            ushort_t pv[16];
            for (int jj = 0; jj < 16; jj++) {
                const float p = __expf(v[jj] - mn);
                sum += p;
                pv[jj] = f2bf(p);
            }
            sum += __shfl_xor(sum, 1, 64);
            sum += __shfl_xor(sum, 2, 64);
            sum += __shfl_xor(sum, 4, 64);
            const float a_ = __expf(mo - mn);
            if (j == 0) { mst[rw] = mn; lst[rw] = lst[rw] * a_ + sum; alp[rw] = a_; }
            for (int jj = 0; jj < 16; jj += 2) {
                unsigned int pk = (unsigned int)pv[jj] | ((unsigned int)pv[jj + 1] << 16);
                *(unsigned int*)&Ps[rw * 136 + j * 16 + jj] = pk;
            }
        }
        __syncthreads();

        // O = O*alpha + P V   (32 d-cols per wave)
        for (int mt = 0; mt < 2; mt++) {
            for (int nt = 0; nt < 2; nt++) {
                for (int rr = 0; rr < 4; rr++) {
                    const int row = mt * 16 + quad * 4 + rr;
                    acc_o[mt][nt][rr] *= alp[row];
                }
            }
        }
        for (int kk = 0; kk < 4; kk++) {
            bf16x8 ap_[2], bv[2];
            for (int mt = 0; mt < 2; mt++)
                ap_[mt] = *(const bf16x8*)&Ps[(mt * 16 + (lane & 15)) * 136 + kk * 32 + quad * 8];
            for (int nt = 0; nt < 2; nt++)
                bv[nt] = *(const bf16x8*)&Vts[(d0w + nt * 16 + (lane & 15)) * 136 + kk * 32 + quad * 8];
            for (int mt = 0; mt < 2; mt++)
                for (int nt = 0; nt < 2; nt++)
                    acc_o[mt][nt] = __builtin_amdgcn_mfma_f32_16x16x32_bf16(
                        ap_[mt], bv[nt], acc_o[mt][nt], 0, 0, 0);
        }
    }

    // epilogue: divide by l, store fp32 to AO (b,k, h*128+d)
    for (int mt = 0; mt < 2; mt++) {
        for (int nt = 0; nt < 2; nt++) {
            const int col = d0w + nt * 16 + (lane & 15);
            for (int rr = 0; rr < 4; rr++) {
                const int row = mt * 16 + quad * 4 + rr;
                AO[(size_t)(b * 64 + k0 + row) * 4096 + h * 128 + col] =
                    acc_o[mt][nt][rr] / lst[row];
            }
        }
    }
}

// ---------------------------------------------------------------------------

extern "C" void kernel_launch(void* const* d_in, const int* in_sizes, int n_in,
                              void* d_out, int out_size, void* d_ws, size_t ws_size,
                              hipStream_t stream) {
    const float* hs    = (const float*)d_in[0];   // hidden_states (4,64,4096) fp32
    const float* th    = (const float*)d_in[1];   // target_hidden (4,4096,4096) fp32
    const float* amask = (const float*)d_in[2];   // attn_mask (4,1,64,4160) fp32
    const float* cosb  = (const float*)d_in[3];   // cos (4,4160,128) fp32
    const float* sinb  = (const float*)d_in[4];   // sin fp32
    const float* Wq    = (const float*)d_in[5];   // (4096,4096) fp32
    const float* Wk    = (const float*)d_in[6];   // (1024,4096) fp32
    const float* Wv    = (const float*)d_in[7];   // (1024,4096) fp32
    const float* Wo    = (const float*)d_in[8];   // (4096,4096) fp32
    const float* qw    = (const float*)d_in[9];   // (128,) fp32
    const float* kw    = (const float*)d_in[10];  // (128,) fp32
    float* out = (float*)d_out;                   // (4,64,4096) fp32

    char* ws = (char*)d_ws;
    ushort_t* Kc = (ushort_t*)(ws);                     // (4,4160,1024) bf16 = 34 MB
    ushort_t* Vc = (ushort_t*)(ws + 34078720);          // 34 MB
    ushort_t* Qb = (ushort_t*)(ws + 68157440);          // (256,4096) bf16 = 2 MB
    float*    AO = (float*)   (ws + 70254592);          // (256,4096) fp32 = 4 MB

    // 1) ctx K and V projections (dominant GEMM), fused over N segments
    gemm_bt<<<dim3(16, 128), 256, 0, stream>>>(th, 16384,
        Wk, Kc, 8, 1, 0,
        Wv, Vc, 8, 1, 0,
        Wv, Vc, 1, 0);
    // 2) noise Q / K / V projections
    gemm_bt<<<dim3(48, 2), 256, 0, stream>>>(hs, 256,
        Wq, Qb, 32, 0, 4096,
        Wk, Kc, 8, 2, 0,
        Wv, Vc, 2, 0);
    // 3) rmsnorm + rope on K cache (all 4160 positions) and Q
    norm_rope<<<33280, 256, 0, stream>>>(Kc, cosb, sinb, kw, 0);
    norm_rope<<<2048, 256, 0, stream>>>(Qb, cosb, sinb, qw, 1);
    // 4) flash attention
    attn_kernel<<<256, 256, 0, stream>>>(Qb, Kc, Vc, amask, AO);
    // 5) output projection (fp32 A from AO, fp32 out)
    gemm_bt<<<dim3(32, 2), 256, 0, stream>>>(AO, 256,
        Wo, out, 32, 3, 4096,
        Wo, out, 0, 3, 4096,
        Wo, out, 3, 4096);
}